// Round 3
// baseline (534.797 us; speedup 1.0000x reference)
//
#include <hip/hip_runtime.h>

// ---------------------------------------------------------------------------
// Fixed problem shape: B=2, T=1024, D=4096, N=32 q-heads, KH=8 kv-heads, H=128.
// ---------------------------------------------------------------------------
constexpr int Bc  = 2;
constexpr int Tc  = 1024;
constexpr int Dc  = 4096;
constexpr int NHc = 32;
constexpr int KHc = 8;
constexpr int Hc  = 128;

typedef __bf16 bf16;
typedef bf16  bf16x4  __attribute__((ext_vector_type(4)));
typedef bf16  bf16x8  __attribute__((ext_vector_type(8)));
typedef float floatx4 __attribute__((ext_vector_type(4)));

#define MFMA16(a, b, c) __builtin_amdgcn_mfma_f32_16x16x32_bf16((a), (b), (c), 0, 0, 0)

// Async global->LDS DMA, 16 B/lane. LDS dest is wave-uniform base + lane*16
// (m104/m108) — lane->LDS map fixed; we pick each lane's GLOBAL source to
// implement swizzled tile layouts for free.
__device__ __forceinline__ void gload_lds16(const bf16* g, bf16* l) {
    __builtin_amdgcn_global_load_lds(
        (const __attribute__((address_space(1))) void*)g,
        (__attribute__((address_space(3))) void*)l, 16, 0, 0);
}

// ---------------------------------------------------------------------------
// start[b] = index of first nonzero segment id.
// ---------------------------------------------------------------------------
__global__ void seg_scan(const int* __restrict__ seg, int* __restrict__ start) {
    int b = threadIdx.x;
    if (b >= Bc) return;
    int f = 0;
    for (int t = 0; t < Tc; ++t) {
        if (seg[b * Tc + t] != 0) { f = t; break; }
    }
    start[b] = f;
}

// ---------------------------------------------------------------------------
// fp32 -> bf16 convert (x pre-pass), 8 elems/thread vectorized.
// ---------------------------------------------------------------------------
__global__ __launch_bounds__(256) void cvt_f32_bf16(const float* __restrict__ in,
                                                    bf16* __restrict__ out) {
    const size_t i = ((size_t)blockIdx.x * 256 + threadIdx.x) * 8;
    float4 f0 = *(const float4*)(in + i);
    float4 f1 = *(const float4*)(in + i + 4);
    bf16x8 v;
    v[0] = (bf16)f0.x; v[1] = (bf16)f0.y; v[2] = (bf16)f0.z; v[3] = (bf16)f0.w;
    v[4] = (bf16)f1.x; v[5] = (bf16)f1.y; v[6] = (bf16)f1.z; v[7] = (bf16)f1.w;
    *(bf16x8*)(out + i) = v;
}

// ---------------------------------------------------------------------------
// Transpose + fp32->bf16 convert: out[C x R] = in[R x C]^T. 64x64 tile,
// float4 loads (16 B/lane), bf16x4 stores (8 B/lane), +1 pad (2-way banks).
// ---------------------------------------------------------------------------
__global__ __launch_bounds__(256) void transpose_cvt(const float* __restrict__ in,
                                                     bf16* __restrict__ out,
                                                     int R, int C) {
    __shared__ float tile[64][65];
    const int c0 = blockIdx.x * 64, r0 = blockIdx.y * 64;
    const int tx = threadIdx.x & 15, ty = threadIdx.x >> 4;   // 16 x 16
#pragma unroll
    for (int i = 0; i < 4; ++i) {
        float4 f = *(const float4*)&in[(size_t)(r0 + ty * 4 + i) * C + c0 + tx * 4];
        tile[ty * 4 + i][tx * 4 + 0] = f.x;
        tile[ty * 4 + i][tx * 4 + 1] = f.y;
        tile[ty * 4 + i][tx * 4 + 2] = f.z;
        tile[ty * 4 + i][tx * 4 + 3] = f.w;
    }
    __syncthreads();
#pragma unroll
    for (int i = 0; i < 4; ++i) {
        const int cc = ty * 4 + i;
        bf16x4 v;
        v[0] = (bf16)tile[tx * 4 + 0][cc];
        v[1] = (bf16)tile[tx * 4 + 1][cc];
        v[2] = (bf16)tile[tx * 4 + 2][cc];
        v[3] = (bf16)tile[tx * 4 + 3][cc];
        *(bf16x4*)&out[(size_t)(c0 + cc) * R + r0 + tx * 4] = v;
    }
}

// ---------------------------------------------------------------------------
// V transpose: src = qkvb v-columns (strided rows), dst[b][kh][d][t] dense.
// Per block: one (b,kh), 32 t x 128 d tile.
// ---------------------------------------------------------------------------
__global__ __launch_bounds__(256) void v_transpose(const bf16* __restrict__ src,
                                                   bf16* __restrict__ dst,
                                                   int srcstride) {
    __shared__ bf16 tl[32][136];                 // 272B rows: 16B-aligned
    const int bk = blockIdx.y;                   // b*KHc + kh
    const int b = bk / KHc, kh = bk % KHc;
    const int t0 = blockIdx.x * 32;
    const int tid = threadIdx.x;
    {
        const int j = tid >> 3;                  // t row 0..31
        const int c = tid & 7;                   // d chunk of 16
        const bf16* p = src + (size_t)(b * Tc + t0 + j) * srcstride + kh * Hc + c * 16;
        *(bf16x8*)&tl[j][c * 16]     = *(const bf16x8*)p;
        *(bf16x8*)&tl[j][c * 16 + 8] = *(const bf16x8*)(p + 8);
    }
    __syncthreads();
    {
        const int d = tid >> 1;                  // 0..127
        const int toff = (tid & 1) * 16;
        bf16x8 v0, v1;
#pragma unroll
        for (int k = 0; k < 8; ++k) v0[k] = tl[toff + k][d];
#pragma unroll
        for (int k = 0; k < 8; ++k) v1[k] = tl[toff + 8 + k][d];
        bf16* o = dst + ((size_t)bk * Hc + d) * Tc + t0 + toff;
        *(bf16x8*)o       = v0;
        *(bf16x8*)(o + 8) = v1;
    }
}

// ---------------------------------------------------------------------------
// m97-class MFMA GEMM: C[M x N] = A[M x K] * Bt[N x K]^T, bf16 in.
// 128x128 tile, BK=32, global_load_lds width=16, XOR chunk swizzle.
// (kept for the out-projection: its grid 32x16=512 blocks beats a 50%-CU
// 256^2 launch at that shape)
// ---------------------------------------------------------------------------
template <typename OT>
__global__ __launch_bounds__(256) void gemm128(const bf16* __restrict__ A,
                                               const bf16* __restrict__ Bt,
                                               OT* __restrict__ C,
                                               int M, int K, int N) {
    __shared__ alignas(16) bf16 As[128 * 32];
    __shared__ alignas(16) bf16 Bs[128 * 32];
    const int m0 = blockIdx.y * 128, n0 = blockIdx.x * 128;
    const int tid = threadIdx.x;
    const int w = tid >> 6, L = tid & 63, quad = L >> 4, lid = L & 15;
    const int wm = (w & 1) * 64, wn = (w >> 1) * 64;

    const int srow = w * 32 + (L >> 2);
    const int chk  = (L & 3) ^ ((L >> 3) & 3);
    const bf16* gA = A  + (size_t)(m0 + srow) * K + chk * 8;
    const bf16* gB = Bt + (size_t)(n0 + srow) * K + chk * 8;
    bf16* lA0 = &As[(w * 32) * 32];
    bf16* lA1 = &As[(w * 32 + 16) * 32];
    bf16* lB0 = &Bs[(w * 32) * 32];
    bf16* lB1 = &Bs[(w * 32 + 16) * 32];

    const bf16* ap[4]; const bf16* bp[4];
#pragma unroll
    for (int i = 0; i < 4; ++i) {
        const int ra = wm + i * 16 + lid;
        ap[i] = &As[ra * 32 + (quad ^ ((ra >> 1) & 3)) * 8];
        const int rb = wn + i * 16 + lid;
        bp[i] = &Bs[rb * 32 + (quad ^ ((rb >> 1) & 3)) * 8];
    }

    floatx4 acc[4][4] = {};

    for (int k0 = 0; k0 < K; k0 += 32) {
        __syncthreads();
        gload_lds16(gA + k0,                  lA0);
        gload_lds16(gA + (size_t)16 * K + k0, lA1);
        gload_lds16(gB + k0,                  lB0);
        gload_lds16(gB + (size_t)16 * K + k0, lB1);
        __syncthreads();

        bf16x8 af[4], bfr[4];
#pragma unroll
        for (int i = 0; i < 4; ++i) af[i]  = *(const bf16x8*)ap[i];
#pragma unroll
        for (int j = 0; j < 4; ++j) bfr[j] = *(const bf16x8*)bp[j];
#pragma unroll
        for (int i = 0; i < 4; ++i)
#pragma unroll
            for (int j = 0; j < 4; ++j)
                acc[i][j] = MFMA16(af[i], bfr[j], acc[i][j]);
    }

#pragma unroll
    for (int i = 0; i < 4; ++i) {
#pragma unroll
        for (int r = 0; r < 4; ++r) {
            const size_t row = (size_t)(m0 + wm + i * 16 + quad * 4 + r);
#pragma unroll
            for (int j = 0; j < 4; ++j)
                C[row * N + (n0 + wn + j * 16 + lid)] = (OT)acc[i][j][r];
        }
    }
}

// ---------------------------------------------------------------------------
// R6: ring256 + 2-phase-per-K32 interleave (T3 at the proven template grain).
// 256x256 tile, 8 waves (2x4), BK=32, 4-slot LDS ring (128 KB), counted
// vmcnt (T4), raw barriers, setprio around MFMA clusters (T5).
// Phase grain matches the m201 template: 16 MFMA / phase, 8-or-4 ds_read_b128
// + 2 global_load_lds per phase, barrier -> lgkmcnt(0) -> sched_barrier ->
// MFMA -> barrier.
// Sync ledger (unchanged from R5, stages split across phases):
//   - iter t stages tile t+3 into slot (t+3)&3 == (t-1)&3. All reads of that
//     slot (iter t-1, both phases) are lgkmcnt-drained before their consuming
//     MFMAs, which precede iter t-1's closing barrier; iter t's stages are
//     issued after it. No read/write race.
//   - end-of-iter vmcnt(8): outstanding <= {iter t: 4, iter t-1: 4}; tile
//     t+1's 4 loads (iter t-2) are older => drained before iter t+1 reads.
//   - post-loop vmcnt(0): no LDS-DMA in flight at endpgm.
// Requires: M%256==0, N%256==0, K%32==0, (K/32)%4==0.
// ---------------------------------------------------------------------------
template <typename OT>
__global__ __launch_bounds__(512, 2) void gemm_ring256(const bf16* __restrict__ A,
                                                       const bf16* __restrict__ Bt,
                                                       OT* __restrict__ C,
                                                       int M, int K, int N) {
    // slot layout: A[256][32] at 0, B[256][32] at elem 8192. 16384 elems/slot.
    __shared__ alignas(16) bf16 ring[4][16384];
    const int m0 = blockIdx.y * 256, n0 = blockIdx.x * 256;
    const int tid = threadIdx.x;
    const int w = tid >> 6, L = tid & 63, quad = L >> 4, lid = L & 15;
    const int wr = w >> 2, wc = w & 3;           // 2 x 4 wave grid

    // ---- staging geometry: 4 x global_load_lds(16B) per thread per tile ----
    // instr covers 128 rows (512 thr x 16B = 8 KB); row = tid>>2, chunk slot
    // c = tid&3 holds global chunk c ^ ((row>>1)&3) (involution; linear LDS
    // dest + inverse-swizzled global source, per rule #21).
    const int srow = tid >> 2;                               // 0..127
    const int schk = ((tid & 3) ^ ((tid >> 3) & 3)) * 8;     // swizzled k-chunk
    const bf16* gA0 = A  + (size_t)(m0 + srow) * K + schk;
    const bf16* gA1 = A  + (size_t)(m0 + 128 + srow) * K + schk;
    const bf16* gB0 = Bt + (size_t)(n0 + srow) * K + schk;
    const bf16* gB1 = Bt + (size_t)(n0 + 128 + srow) * K + schk;
    // wave-uniform LDS bases (elems within slot)
    const int ldsA0 = (w * 16) * 32;
    const int ldsA1 = (128 + w * 16) * 32;
    const int ldsB0 = 8192 + (w * 16) * 32;
    const int ldsB1 = 8192 + (128 + w * 16) * 32;

    // ---- fragment offsets (swizzled read side, 2-way banks = free) ----
    int offA[8], offB[4];
#pragma unroll
    for (int m = 0; m < 8; ++m) {
        const int row = wr * 128 + m * 16 + lid;
        offA[m] = row * 32 + ((quad ^ ((row >> 1) & 3)) * 8);
    }
#pragma unroll
    for (int n = 0; n < 4; ++n) {
        const int row = wc * 64 + n * 16 + lid;
        offB[n] = 8192 + row * 32 + ((quad ^ ((row >> 1) & 3)) * 8);
    }

    const int NT = K >> 5;                       // K/32; NT % 4 == 0 required

    auto stageA = [&](int kt) {                  // kt pre-wrapped; slot = kt&3
        bf16* sb = ring[kt & 3];
        const size_t ko = (size_t)kt << 5;
        gload_lds16(gA0 + ko, sb + ldsA0);
        gload_lds16(gA1 + ko, sb + ldsA1);
    };
    auto stageB = [&](int kt) {
        bf16* sb = ring[kt & 3];
        const size_t ko = (size_t)kt << 5;
        gload_lds16(gB0 + ko, sb + ldsB0);
        gload_lds16(gB1 + ko, sb + ldsB1);
    };

    // prologue: tiles 0..2 in flight; wait tile 0 (8 = tiles 1,2 outstanding)
    stageA(0); stageB(0); stageA(1); stageB(1); stageA(2); stageB(2);
    asm volatile("s_waitcnt vmcnt(8)" ::: "memory");
    __builtin_amdgcn_s_barrier();
    __builtin_amdgcn_sched_barrier(0);

    floatx4 acc[8][4] = {};

    for (int t = 0; t < NT; ++t) {
        int ts = t + 3; if (ts >= NT) ts -= NT;  // wrap: tail re-stages 0..2
        const bf16* sb = ring[t & 3];

        // ================= phase 1: m=0..3 quadrant =================
        bf16x8 af0[4], bfr[4];
#pragma unroll
        for (int m = 0; m < 4; ++m) af0[m] = *(const bf16x8*)(sb + offA[m]);
#pragma unroll
        for (int n = 0; n < 4; ++n) bfr[n] = *(const bf16x8*)(sb + offB[n]);
        stageA(ts);                              // 2 gload_lds (A half-tiles)

        __builtin_amdgcn_s_barrier();
        asm volatile("s_waitcnt lgkmcnt(0)" ::: "memory");
        __builtin_amdgcn_sched_barrier(0);
        __builtin_amdgcn_s_setprio(1);
#pragma unroll
        for (int m = 0; m < 4; ++m)
#pragma unroll
            for (int n = 0; n < 4; ++n)
                acc[m][n] = MFMA16(af0[m], bfr[n], acc[m][n]);
        __builtin_amdgcn_s_setprio(0);
        __builtin_amdgcn_s_barrier();
        __builtin_amdgcn_sched_barrier(0);

        // ================= phase 2: m=4..7 quadrant =================
        bf16x8 af1[4];
#pragma unroll
        for (int m = 0; m < 4; ++m) af1[m] = *(const bf16x8*)(sb + offA[4 + m]);
        stageB(ts);                              // 2 gload_lds (B half-tiles)

        __builtin_amdgcn_s_barrier();
        asm volatile("s_waitcnt lgkmcnt(0)" ::: "memory");
        __builtin_amdgcn_sched_barrier(0);
        __builtin_amdgcn_s_setprio(1);
#pragma unroll
        for (int m = 0; m < 4; ++m)
#pragma unroll
            for (int n = 0; n < 4; ++n)
                acc[4 + m][n] = MFMA16(af1[m], bfr[n], acc[4 + m][n]);
        __builtin_amdgcn_s_setprio(0);

        asm volatile("s_waitcnt vmcnt(8)" ::: "memory");  // tile t+1 landed
        __builtin_amdgcn_s_barrier();
        __builtin_amdgcn_sched_barrier(0);
    }

    // Drain remaining LDS-DMAs (wrap-stages) before epilogue/endpgm.
    asm volatile("s_waitcnt vmcnt(0)" ::: "memory");

#pragma unroll
    for (int m = 0; m < 8; ++m) {
#pragma unroll
        for (int r = 0; r < 4; ++r) {
            const size_t row = (size_t)(m0 + wr * 128 + m * 16 + quad * 4 + r);
#pragma unroll
            for (int n = 0; n < 4; ++n)
                C[row * N + (n0 + wc * 64 + n * 16 + lid)] = (OT)acc[m][n][r];
        }
    }
}

// ---------------------------------------------------------------------------
// In-place RMSNorm (+scale) + RoPE; one wave per head-vector (strided buffer).
// ---------------------------------------------------------------------------
__global__ __launch_bounds__(256) void rms_rope(bf16* __restrict__ buf,
                                                const float* __restrict__ scale,
                                                const int* __restrict__ start,
                                                int nheads, int rowstride) {
    const int gid = blockIdx.x * 4 + (threadIdx.x >> 6);
    const int L   = threadIdx.x & 63;
    const int h   = gid % nheads;
    const int t   = (gid / nheads) % Tc;
    const int b   = gid / (nheads * Tc);
    bf16* p = buf + (size_t)(b * Tc + t) * rowstride + h * Hc;

    float x1 = (float)p[L], x2 = (float)p[L + 64];
    float ss = x1 * x1 + x2 * x2;
#pragma unroll
    for (int off = 1; off < 64; off <<= 1) ss += __shfl_xor(ss, off);
    const float inv = 1.f / sqrtf(ss * (1.0f / 128.0f) + 1e-6f);
    const float y1 = scale[L] * x1 * inv;
    const float y2 = scale[L + 64] * x2 * inv;

    const int   pos = t - start[b];
    const float fr  = (float)L * (1.0f / 64.0f);
    const float invf = exp2f(-19.9315686f * fr);   // theta^-fr, theta=1e6
    const float ang = (float)pos * invf;
    float sn, cs;
    sincosf(ang, &sn, &cs);                        // accurate (large args)

    p[L]      = (bf16)(y1 * cs - y2 * sn);
    p[L + 64] = (bf16)(y2 * cs + y1 * sn);
}

// ---------------------------------------------------------------------------
// Causal GQA flash attention, fixed-shift softmax (post-RMSNorm |logit| <=
// 11.3 => p = exp(logit-16), exact after final /sum).
// K tile (32 s x 128 d, natural) and V^T tile (128 d x 32 s) staged via
// global_load_lds with XOR chunk swizzles; shared by all 4 waves.
// ---------------------------------------------------------------------------
__global__ __launch_bounds__(256) void attn_kernel(const bf16* __restrict__ q,
                                                   const bf16* __restrict__ k,
                                                   const bf16* __restrict__ vt,
                                                   bf16* __restrict__ outp,
                                                   const int* __restrict__ start,
                                                   int qstride, int kstride) {
    __shared__ alignas(16) bf16 Ks[32 * 128];    // row s (256 B), swizzled chunks
    __shared__ alignas(16) bf16 VT[128 * 32];    // row d (64 B), swizzled chunks
    __shared__ alignas(16) bf16 pS[4][16][40];   // per-wave P tile

    const int tblk = blockIdx.x, n = blockIdx.y, b = blockIdx.z;
    const int kh   = n >> 2;                     // N/KH = 4
    const int tid  = threadIdx.x, w = tid >> 6, L = tid & 63;
    const int quad = L >> 4, lid = L & 15;
    const int t0   = tblk * 64 + w * 16;
    const int st   = start[b];

    // Q fragments (16 rows x 128 feats) in registers.
    const bf16* qrow = q + (size_t)(b * Tc + t0 + lid) * qstride + n * Hc;
    bf16x8 aqf[4];
#pragma unroll
    for (int c = 0; c < 4; ++c) aqf[c] = *(const bf16x8*)(qrow + c * 32 + quad * 8);

    // K staging: instr i covers rows w*8+4i..+3; lane row = +L>>4, stored
    // chunk p=L&15 holds logical chunk p^(row&15).
    const int kr0 = w * 8 + (L >> 4);
    const int kr1 = kr0 + 4;
    const bf16* gK0 = k + (size_t)(b * Tc + kr0) * kstride + kh * Hc
                        + (((L & 15) ^ (kr0 & 15)) * 8);
    const bf16* gK1 = k + (size_t)(b * Tc + kr1) * kstride + kh * Hc
                        + (((L & 15) ^ (kr1 & 15)) * 8);
    bf16* lK0 = &Ks[(w * 8) * 128];
    bf16* lK1 = &Ks[(w * 8 + 4) * 128];

    // V^T staging: instr i covers d-rows (w*2+i)*16..+15; lane d = +L>>2,
    // stored pos p=L&3 holds logical chunk p^(d&3)^((d>>2)&3).
    const int vd0 = (w * 2) * 16 + (L >> 2);
    const int vd1 = vd0 + 16;
    const bf16* vbase = vt + (size_t)((b * KHc + kh) * Hc) * Tc;
    const bf16* gV0 = vbase + (size_t)vd0 * Tc + (((L & 3) ^ (vd0 & 3) ^ ((vd0 >> 2) & 3)) * 8);
    const bf16* gV1 = vbase + (size_t)vd1 * Tc + (((L & 3) ^ (vd1 & 3) ^ ((vd1 >> 2) & 3)) * 8);
    bf16* lV0 = &VT[(w * 2) * 512];
    bf16* lV1 = &VT[(w * 2 + 1) * 512];

    // Loop-invariant swizzled fragment pointers.
    const bf16* kf[4][2];
#pragma unroll
    for (int c = 0; c < 4; ++c) {
        kf[c][0] = &Ks[lid * 128        + (((c * 4 + quad) ^ lid) * 8)];
        kf[c][1] = &Ks[(16 + lid) * 128 + (((c * 4 + quad) ^ lid) * 8)];
    }
    const int vpos = (quad ^ (lid & 3) ^ ((lid >> 2) & 3)) * 8;
    const bf16* vf[8];
#pragma unroll
    for (int cg = 0; cg < 8; ++cg) vf[cg] = &VT[(cg * 16 + lid) * 32 + vpos];

    floatx4 oacc[8] = {};
    float lsum[4] = {0.f, 0.f, 0.f, 0.f};
    const int sEnd = tblk * 64 + 64;

    for (int s0 = 0; s0 < sEnd; s0 += 32) {
        __syncthreads();                         // prior-iter LDS reads done
        gload_lds16(gK0 + (size_t)s0 * kstride, lK0);
        gload_lds16(gK1 + (size_t)s0 * kstride, lK1);
        gload_lds16(gV0 + s0, lV0);
        gload_lds16(gV1 + s0, lV1);
        __syncthreads();                         // DMA drained

        // ---- QK^T: 16 q x 32 keys ----
        floatx4 sc0 = {0.f, 0.f, 0.f, 0.f}, sc1 = {0.f, 0.f, 0.f, 0.f};
#pragma unroll
        for (int c = 0; c < 4; ++c) {
            sc0 = MFMA16(aqf[c], *(const bf16x8*)kf[c][0], sc0);
            sc1 = MFMA16(aqf[c], *(const bf16x8*)kf[c][1], sc1);
        }

        // ---- mask + exp(shift 16) + P to LDS (C->A layout) ----
#pragma unroll
        for (int r = 0; r < 4; ++r) {
            const int tq  = t0 + quad * 4 + r;
            const int sk0 = s0 + lid, sk1 = s0 + 16 + lid;
            const float p0 = (sk0 <= tq && sk0 >= st)
                               ? __expf(sc0[r] * 0.08838834764831845f - 16.f) : 0.f;
            const float p1 = (sk1 <= tq && sk1 >= st)
                               ? __expf(sc1[r] * 0.08838834764831845f - 16.f) : 0.f;
            lsum[r] += p0 + p1;
            pS[w][quad * 4 + r][lid]      = (bf16)p0;
            pS[w][quad * 4 + r][16 + lid] = (bf16)p1;
        }
        asm volatile("s_waitcnt lgkmcnt(0)" ::: "memory");  // same-wave RAW

        // ---- PV: P (16x32) * V (32x128) ----
        bf16x8 pa = *(const bf16x8*)&pS[w][lid][quad * 8];
#pragma unroll
        for (int cg = 0; cg < 8; ++cg)
            oacc[cg] = MFMA16(pa, *(const bf16x8*)vf[cg], oacc[cg]);
    }

#pragma unroll
    for (int r = 0; r < 4; ++r) {
        lsum[r] += __shfl_xor(lsum[r], 1);
        lsum[r] += __shfl_xor(lsum[r], 2);
        lsum[r] += __shfl_xor(lsum[r], 4);
        lsum[r] += __shfl_xor(lsum[r], 8);
    }

#pragma unroll
    for (int cg = 0; cg < 8; ++cg) {
#pragma unroll
        for (int r = 0; r < 4; ++r) {
            const int t = t0 + quad * 4 + r;
            outp[((size_t)(b * Tc + t) * NHc + n) * Hc + cg * 16 + lid] =
                (bf16)(oacc[cg][r] / lsum[r]);
        }
    }
}

// ---------------------------------------------------------------------------
// Workspace layout (88 MB + 8 B):
//   [0,48M)  wcomb : [wqT;wkT;wvT] (6144 x 4096 bf16). After the QKV GEMM,
//            [0,32M) is overwritten by woT and [32,36M) by vtb (wkT dead).
//   [48,72M) qkvb  : [2048][6144] bf16 (q: 0-4095, k: 4096-5119, v: 5120-6143)
//   [72,88M) xb (bf16 x) -> overlaid by ab (attention out) after QKV GEMM
//   [88M)    start[B]
// ---------------------------------------------------------------------------
extern "C" void kernel_launch(void* const* d_in, const int* in_sizes, int n_in,
                              void* d_out, int out_size, void* d_ws, size_t ws_size,
                              hipStream_t stream) {
    const float* x       = (const float*)d_in[0];
    const float* wq      = (const float*)d_in[1];
    const float* wk      = (const float*)d_in[2];
    const float* wv      = (const float*)d_in[3];
    const float* wo      = (const float*)d_in[4];
    const float* q_scale = (const float*)d_in[5];
    const float* k_scale = (const float*)d_in[6];
    const int*   seg     = (const int*)d_in[9];
    float*       out     = (float*)d_out;

    char* ws = (char*)d_ws;
    bf16* wcomb = (bf16*)(ws);
    bf16* vtb   = (bf16*)(ws + (32ull << 20));      // overlay: dead wkT region
    bf16* qkvb  = (bf16*)(ws + (48ull << 20));
    bf16* xb    = (bf16*)(ws + (72ull << 20));
    bf16* ab    = xb;                               // overlay (xb dead by then)
    int*  stb   = (int*) (ws + (88ull << 20));

    seg_scan<<<1, 64, 0, stream>>>(seg, stb);

    cvt_f32_bf16<<<(Bc * Tc * Dc) / (256 * 8), 256, 0, stream>>>(x, xb);

    transpose_cvt<<<dim3(64, 64), 256, 0, stream>>>(wq, wcomb, Dc, NHc * Hc);
    transpose_cvt<<<dim3(16, 64), 256, 0, stream>>>(wk, wcomb + (size_t)4096 * Dc, Dc, KHc * Hc);
    transpose_cvt<<<dim3(16, 64), 256, 0, stream>>>(wv, wcomb + (size_t)5120 * Dc, Dc, KHc * Hc);

    // Fused QKV projection: [2048 x 4096] * [6144 x 4096]^T -> [2048 x 6144]
    // Ring-pipelined 256^2 kernel, 2-phase interleave (24 x 8 = 192 wg, 512 thr).
    gemm_ring256<bf16><<<dim3(24, 8), 512, 0, stream>>>(xb, wcomb, qkvb,
                                                        Bc * Tc, Dc, 6144);

    rms_rope<<<(Bc * Tc * NHc) / 4, 256, 0, stream>>>(qkvb, q_scale, stb, NHc, 6144);
    rms_rope<<<(Bc * Tc * KHc) / 4, 256, 0, stream>>>(qkvb + 4096, k_scale, stb, KHc, 6144);

    v_transpose<<<dim3(Tc / 32, Bc * KHc), 256, 0, stream>>>(qkvb + 5120, vtb, 6144);

    // woT into wcomb[0,32M) (wqT dead after QKV GEMM).
    transpose_cvt<<<dim3(64, 64), 256, 0, stream>>>(wo, wcomb, NHc * Hc, Dc);

    attn_kernel<<<dim3(Tc / 64, NHc, Bc), 256, 0, stream>>>(
        qkvb, qkvb + 4096, vtb, ab, stb, 6144, 6144);

    // Out projection: [2048 x 4096] * [4096 x 4096]^T -> [2048 x 4096] fp32
    gemm128<float><<<dim3(32, 16), 256, 0, stream>>>(ab, wcomb, out,
                                                     Bc * Tc, NHc * Hc, Dc);
}

// Round 4
// 520.740 us; speedup vs baseline: 1.0270x; 1.0270x over previous
//
#include <hip/hip_runtime.h>

// ---------------------------------------------------------------------------
// Fixed problem shape: B=2, T=1024, D=4096, N=32 q-heads, KH=8 kv-heads, H=128.
// ---------------------------------------------------------------------------
constexpr int Bc  = 2;
constexpr int Tc  = 1024;
constexpr int Dc  = 4096;
constexpr int NHc = 32;
constexpr int KHc = 8;
constexpr int Hc  = 128;

typedef __bf16 bf16;
typedef bf16  bf16x4  __attribute__((ext_vector_type(4)));
typedef bf16  bf16x8  __attribute__((ext_vector_type(8)));
typedef float floatx4 __attribute__((ext_vector_type(4)));

#define MFMA16(a, b, c) __builtin_amdgcn_mfma_f32_16x16x32_bf16((a), (b), (c), 0, 0, 0)

// Async global->LDS DMA, 16 B/lane. LDS dest is wave-uniform base + lane*16
// (m104/m108) — lane->LDS map fixed; we pick each lane's GLOBAL source to
// implement swizzled tile layouts for free.
__device__ __forceinline__ void gload_lds16(const bf16* g, bf16* l) {
    __builtin_amdgcn_global_load_lds(
        (const __attribute__((address_space(1))) void*)g,
        (__attribute__((address_space(3))) void*)l, 16, 0, 0);
}

// ---------------------------------------------------------------------------
// start[b] = index of first nonzero segment id.
// ---------------------------------------------------------------------------
__global__ void seg_scan(const int* __restrict__ seg, int* __restrict__ start) {
    int b = threadIdx.x;
    if (b >= Bc) return;
    int f = 0;
    for (int t = 0; t < Tc; ++t) {
        if (seg[b * Tc + t] != 0) { f = t; break; }
    }
    start[b] = f;
}

// ---------------------------------------------------------------------------
// fp32 -> bf16 convert (x pre-pass), 8 elems/thread vectorized.
// ---------------------------------------------------------------------------
__global__ __launch_bounds__(256) void cvt_f32_bf16(const float* __restrict__ in,
                                                    bf16* __restrict__ out) {
    const size_t i = ((size_t)blockIdx.x * 256 + threadIdx.x) * 8;
    float4 f0 = *(const float4*)(in + i);
    float4 f1 = *(const float4*)(in + i + 4);
    bf16x8 v;
    v[0] = (bf16)f0.x; v[1] = (bf16)f0.y; v[2] = (bf16)f0.z; v[3] = (bf16)f0.w;
    v[4] = (bf16)f1.x; v[5] = (bf16)f1.y; v[6] = (bf16)f1.z; v[7] = (bf16)f1.w;
    *(bf16x8*)(out + i) = v;
}

// ---------------------------------------------------------------------------
// Transpose + fp32->bf16 convert: out[C x R] = in[R x C]^T. 64x64 tile,
// float4 loads (16 B/lane), bf16x4 stores (8 B/lane), +1 pad (2-way banks).
// ---------------------------------------------------------------------------
__global__ __launch_bounds__(256) void transpose_cvt(const float* __restrict__ in,
                                                     bf16* __restrict__ out,
                                                     int R, int C) {
    __shared__ float tile[64][65];
    const int c0 = blockIdx.x * 64, r0 = blockIdx.y * 64;
    const int tx = threadIdx.x & 15, ty = threadIdx.x >> 4;   // 16 x 16
#pragma unroll
    for (int i = 0; i < 4; ++i) {
        float4 f = *(const float4*)&in[(size_t)(r0 + ty * 4 + i) * C + c0 + tx * 4];
        tile[ty * 4 + i][tx * 4 + 0] = f.x;
        tile[ty * 4 + i][tx * 4 + 1] = f.y;
        tile[ty * 4 + i][tx * 4 + 2] = f.z;
        tile[ty * 4 + i][tx * 4 + 3] = f.w;
    }
    __syncthreads();
#pragma unroll
    for (int i = 0; i < 4; ++i) {
        const int cc = ty * 4 + i;
        bf16x4 v;
        v[0] = (bf16)tile[tx * 4 + 0][cc];
        v[1] = (bf16)tile[tx * 4 + 1][cc];
        v[2] = (bf16)tile[tx * 4 + 2][cc];
        v[3] = (bf16)tile[tx * 4 + 3][cc];
        *(bf16x4*)&out[(size_t)(c0 + cc) * R + r0 + tx * 4] = v;
    }
}

// ---------------------------------------------------------------------------
// V transpose: src = qkvb v-columns (strided rows), dst[b][kh][d][t] dense.
// Per block: one (b,kh), 32 t x 128 d tile.
// ---------------------------------------------------------------------------
__global__ __launch_bounds__(256) void v_transpose(const bf16* __restrict__ src,
                                                   bf16* __restrict__ dst,
                                                   int srcstride) {
    __shared__ bf16 tl[32][136];                 // 272B rows: 16B-aligned
    const int bk = blockIdx.y;                   // b*KHc + kh
    const int b = bk / KHc, kh = bk % KHc;
    const int t0 = blockIdx.x * 32;
    const int tid = threadIdx.x;
    {
        const int j = tid >> 3;                  // t row 0..31
        const int c = tid & 7;                   // d chunk of 16
        const bf16* p = src + (size_t)(b * Tc + t0 + j) * srcstride + kh * Hc + c * 16;
        *(bf16x8*)&tl[j][c * 16]     = *(const bf16x8*)p;
        *(bf16x8*)&tl[j][c * 16 + 8] = *(const bf16x8*)(p + 8);
    }
    __syncthreads();
    {
        const int d = tid >> 1;                  // 0..127
        const int toff = (tid & 1) * 16;
        bf16x8 v0, v1;
#pragma unroll
        for (int k = 0; k < 8; ++k) v0[k] = tl[toff + k][d];
#pragma unroll
        for (int k = 0; k < 8; ++k) v1[k] = tl[toff + 8 + k][d];
        bf16* o = dst + ((size_t)bk * Hc + d) * Tc + t0 + toff;
        *(bf16x8*)o       = v0;
        *(bf16x8*)(o + 8) = v1;
    }
}

// ---------------------------------------------------------------------------
// m97-class MFMA GEMM: C[M x N] = A[M x K] * Bt[N x K]^T, bf16 in.
// 128x128 tile, BK=32, global_load_lds width=16, XOR chunk swizzle.
// (kept for the out-projection this round)
// ---------------------------------------------------------------------------
template <typename OT>
__global__ __launch_bounds__(256) void gemm128(const bf16* __restrict__ A,
                                               const bf16* __restrict__ Bt,
                                               OT* __restrict__ C,
                                               int M, int K, int N) {
    __shared__ alignas(16) bf16 As[128 * 32];
    __shared__ alignas(16) bf16 Bs[128 * 32];
    const int m0 = blockIdx.y * 128, n0 = blockIdx.x * 128;
    const int tid = threadIdx.x;
    const int w = tid >> 6, L = tid & 63, quad = L >> 4, lid = L & 15;
    const int wm = (w & 1) * 64, wn = (w >> 1) * 64;

    const int srow = w * 32 + (L >> 2);
    const int chk  = (L & 3) ^ ((L >> 3) & 3);
    const bf16* gA = A  + (size_t)(m0 + srow) * K + chk * 8;
    const bf16* gB = Bt + (size_t)(n0 + srow) * K + chk * 8;
    bf16* lA0 = &As[(w * 32) * 32];
    bf16* lA1 = &As[(w * 32 + 16) * 32];
    bf16* lB0 = &Bs[(w * 32) * 32];
    bf16* lB1 = &Bs[(w * 32 + 16) * 32];

    const bf16* ap[4]; const bf16* bp[4];
#pragma unroll
    for (int i = 0; i < 4; ++i) {
        const int ra = wm + i * 16 + lid;
        ap[i] = &As[ra * 32 + (quad ^ ((ra >> 1) & 3)) * 8];
        const int rb = wn + i * 16 + lid;
        bp[i] = &Bs[rb * 32 + (quad ^ ((rb >> 1) & 3)) * 8];
    }

    floatx4 acc[4][4] = {};

    for (int k0 = 0; k0 < K; k0 += 32) {
        __syncthreads();
        gload_lds16(gA + k0,                  lA0);
        gload_lds16(gA + (size_t)16 * K + k0, lA1);
        gload_lds16(gB + k0,                  lB0);
        gload_lds16(gB + (size_t)16 * K + k0, lB1);
        __syncthreads();

        bf16x8 af[4], bfr[4];
#pragma unroll
        for (int i = 0; i < 4; ++i) af[i]  = *(const bf16x8*)ap[i];
#pragma unroll
        for (int j = 0; j < 4; ++j) bfr[j] = *(const bf16x8*)bp[j];
#pragma unroll
        for (int i = 0; i < 4; ++i)
#pragma unroll
            for (int j = 0; j < 4; ++j)
                acc[i][j] = MFMA16(af[i], bfr[j], acc[i][j]);
    }

#pragma unroll
    for (int i = 0; i < 4; ++i) {
#pragma unroll
        for (int r = 0; r < 4; ++r) {
            const size_t row = (size_t)(m0 + wm + i * 16 + quad * 4 + r);
#pragma unroll
            for (int j = 0; j < 4; ++j)
                C[row * N + (n0 + wn + j * 16 + lid)] = (OT)acc[i][j][r];
        }
    }
}

// ---------------------------------------------------------------------------
// R7: 128x192-tile 4-wave ring-pipelined GEMM, 2 blocks/CU.
//   C[M x N] = A[M x K] * Bt[N x K]^T, bf16 in. BK=32, ring-3 LDS
//   (3 x 20 KB = 60 KB => TWO blocks co-resident per CU; m114: their MFMA
//   and memory phases co-schedule, covering each other's barrier drains).
//   Grid 512 blocks = exactly 2/CU (full coverage vs R5's 192/256).
// Per tile: 5 x global_load_lds(16B)/thread (A:2, B:3, all uniform).
// Sync ledger (rescaled R5, race-free):
//   - iter t stages tile t+2 into slot (t+2)%3 == slot (t-1)%3, whose
//     ds_reads completed before iter t-1's MFMAs (data-dep lgkmcnt), which
//     precede iter t-1's closing barrier; the stage is issued after it.
//   - end-of-iter vmcnt(5): outstanding <= {t+1: 5, t+2: 5}; waiting to 5
//     drains tile t+1 => landed before iter t+1 reads. Never vmcnt(0) in
//     the loop (T4).
//   - raw s_barrier (no compiler drain); post-loop vmcnt(0) before endpgm.
// Requires: M%128==0, N%192==0, K%32==0, K/32 >= 3.
// ---------------------------------------------------------------------------
template <typename OT>
__global__ __launch_bounds__(256, 2) void gemm_ring192(const bf16* __restrict__ A,
                                                       const bf16* __restrict__ Bt,
                                                       OT* __restrict__ C,
                                                       int M, int K, int N) {
    // slot layout: A[128][32] at elem 0, B[192][32] at elem 4096. 10240/slot.
    __shared__ alignas(16) bf16 ring[3][10240];
    const int m0 = blockIdx.y * 128, n0 = blockIdx.x * 192;
    const int tid = threadIdx.x;
    const int w = tid >> 6, L = tid & 63, quad = L >> 4, lid = L & 15;
    const int wr = w >> 1, wc = w & 1;           // 2 x 2 wave grid

    // ---- staging geometry: 5 x global_load_lds(16B) per thread per tile ----
    // Each instr covers 64 rows (256 thr x 16B = 4 KB); row = base + tid>>2,
    // stored chunk c = tid&3 holds global chunk c ^ ((row>>1)&3)
    // (involution; linear LDS dest + inverse-swizzled source, rule #21).
    // All 64-row bases are ==0 mod 8, so the swizzle formula is shared.
    const int srow = tid >> 2;                               // 0..63
    const int schk = ((tid & 3) ^ ((tid >> 3) & 3)) * 8;     // swizzled k-chunk
    const bf16* gA = A  + (size_t)(m0 + srow) * K + schk;
    const bf16* gB = Bt + (size_t)(n0 + srow) * K + schk;
    const size_t K64 = (size_t)64 * K, K128 = (size_t)128 * K;
    // wave-uniform LDS bases (elems within slot)
    const int ldsA0 = (w * 16) * 32;
    const int ldsA1 = (64 + w * 16) * 32;
    const int ldsB0 = 4096 + (w * 16) * 32;
    const int ldsB1 = 4096 + (64 + w * 16) * 32;
    const int ldsB2 = 4096 + (128 + w * 16) * 32;

    // ---- fragment offsets (swizzled read side, 2-way banks = free) ----
    int offA[4], offB[6];
#pragma unroll
    for (int m = 0; m < 4; ++m) {
        const int row = wr * 64 + m * 16 + lid;
        offA[m] = row * 32 + ((quad ^ ((row >> 1) & 3)) * 8);
    }
#pragma unroll
    for (int n = 0; n < 6; ++n) {
        const int row = wc * 96 + n * 16 + lid;
        offB[n] = 4096 + row * 32 + ((quad ^ ((row >> 1) & 3)) * 8);
    }

    const int NT = K >> 5;                       // K/32

    auto stage = [&](int kt, int sl) {           // kt pre-wrapped; sl = slot
        bf16* sb = ring[sl];
        const size_t ko = (size_t)kt << 5;
        gload_lds16(gA + ko,         sb + ldsA0);
        gload_lds16(gA + K64 + ko,   sb + ldsA1);
        gload_lds16(gB + ko,         sb + ldsB0);
        gload_lds16(gB + K64 + ko,   sb + ldsB1);
        gload_lds16(gB + K128 + ko,  sb + ldsB2);
    };

    // prologue: tiles 0,1 in flight; wait tile 0 (5 = tile 1 outstanding)
    stage(0, 0); stage(1, 1);
    asm volatile("s_waitcnt vmcnt(5)" ::: "memory");
    __builtin_amdgcn_s_barrier();
    __builtin_amdgcn_sched_barrier(0);

    floatx4 acc[4][6] = {};
    int cur = 0;                                 // slot of tile t

    for (int t = 0; t < NT; ++t) {
        int ts = t + 2; if (ts >= NT) ts -= NT;  // wrap: tail re-stages 0,1
        int ss = cur + 2; if (ss >= 3) ss -= 3;  // slot of tile t+2
        stage(ts, ss);                           // (wrap data never consumed)

        const bf16* sb = ring[cur];
        bf16x8 af[4], bfr[6];
#pragma unroll
        for (int m = 0; m < 4; ++m) af[m]  = *(const bf16x8*)(sb + offA[m]);
#pragma unroll
        for (int n = 0; n < 6; ++n) bfr[n] = *(const bf16x8*)(sb + offB[n]);

        __builtin_amdgcn_s_setprio(1);
#pragma unroll
        for (int m = 0; m < 4; ++m)
#pragma unroll
            for (int n = 0; n < 6; ++n)
                acc[m][n] = MFMA16(af[m], bfr[n], acc[m][n]);
        __builtin_amdgcn_s_setprio(0);

        asm volatile("s_waitcnt vmcnt(5)" ::: "memory");  // tile t+1 landed
        __builtin_amdgcn_s_barrier();
        __builtin_amdgcn_sched_barrier(0);
        cur = (cur == 2) ? 0 : cur + 1;
    }

    // Drain remaining LDS-DMAs (wrap-stages) before epilogue/endpgm.
    asm volatile("s_waitcnt vmcnt(0)" ::: "memory");

#pragma unroll
    for (int m = 0; m < 4; ++m) {
#pragma unroll
        for (int r = 0; r < 4; ++r) {
            const size_t row = (size_t)(m0 + wr * 64 + m * 16 + quad * 4 + r);
#pragma unroll
            for (int n = 0; n < 6; ++n)
                C[row * N + (n0 + wc * 96 + n * 16 + lid)] = (OT)acc[m][n][r];
        }
    }
}

// ---------------------------------------------------------------------------
// In-place RMSNorm (+scale) + RoPE; one wave per head-vector (strided buffer).
// ---------------------------------------------------------------------------
__global__ __launch_bounds__(256) void rms_rope(bf16* __restrict__ buf,
                                                const float* __restrict__ scale,
                                                const int* __restrict__ start,
                                                int nheads, int rowstride) {
    const int gid = blockIdx.x * 4 + (threadIdx.x >> 6);
    const int L   = threadIdx.x & 63;
    const int h   = gid % nheads;
    const int t   = (gid / nheads) % Tc;
    const int b   = gid / (nheads * Tc);
    bf16* p = buf + (size_t)(b * Tc + t) * rowstride + h * Hc;

    float x1 = (float)p[L], x2 = (float)p[L + 64];
    float ss = x1 * x1 + x2 * x2;
#pragma unroll
    for (int off = 1; off < 64; off <<= 1) ss += __shfl_xor(ss, off);
    const float inv = 1.f / sqrtf(ss * (1.0f / 128.0f) + 1e-6f);
    const float y1 = scale[L] * x1 * inv;
    const float y2 = scale[L + 64] * x2 * inv;

    const int   pos = t - start[b];
    const float fr  = (float)L * (1.0f / 64.0f);
    const float invf = exp2f(-19.9315686f * fr);   // theta^-fr, theta=1e6
    const float ang = (float)pos * invf;
    float sn, cs;
    sincosf(ang, &sn, &cs);                        // accurate (large args)

    p[L]      = (bf16)(y1 * cs - y2 * sn);
    p[L + 64] = (bf16)(y2 * cs + y1 * sn);
}

// ---------------------------------------------------------------------------
// Causal GQA flash attention, fixed-shift softmax (post-RMSNorm |logit| <=
// 11.3 => p = exp(logit-16), exact after final /sum).
// K tile (32 s x 128 d, natural) and V^T tile (128 d x 32 s) staged via
// global_load_lds with XOR chunk swizzles; shared by all 4 waves.
// ---------------------------------------------------------------------------
__global__ __launch_bounds__(256) void attn_kernel(const bf16* __restrict__ q,
                                                   const bf16* __restrict__ k,
                                                   const bf16* __restrict__ vt,
                                                   bf16* __restrict__ outp,
                                                   const int* __restrict__ start,
                                                   int qstride, int kstride) {
    __shared__ alignas(16) bf16 Ks[32 * 128];    // row s (256 B), swizzled chunks
    __shared__ alignas(16) bf16 VT[128 * 32];    // row d (64 B), swizzled chunks
    __shared__ alignas(16) bf16 pS[4][16][40];   // per-wave P tile

    const int tblk = blockIdx.x, n = blockIdx.y, b = blockIdx.z;
    const int kh   = n >> 2;                     // N/KH = 4
    const int tid  = threadIdx.x, w = tid >> 6, L = tid & 63;
    const int quad = L >> 4, lid = L & 15;
    const int t0   = tblk * 64 + w * 16;
    const int st   = start[b];

    // Q fragments (16 rows x 128 feats) in registers.
    const bf16* qrow = q + (size_t)(b * Tc + t0 + lid) * qstride + n * Hc;
    bf16x8 aqf[4];
#pragma unroll
    for (int c = 0; c < 4; ++c) aqf[c] = *(const bf16x8*)(qrow + c * 32 + quad * 8);

    // K staging: instr i covers rows w*8+4i..+3; lane row = +L>>4, stored
    // chunk p=L&15 holds logical chunk p^(row&15).
    const int kr0 = w * 8 + (L >> 4);
    const int kr1 = kr0 + 4;
    const bf16* gK0 = k + (size_t)(b * Tc + kr0) * kstride + kh * Hc
                        + (((L & 15) ^ (kr0 & 15)) * 8);
    const bf16* gK1 = k + (size_t)(b * Tc + kr1) * kstride + kh * Hc
                        + (((L & 15) ^ (kr1 & 15)) * 8);
    bf16* lK0 = &Ks[(w * 8) * 128];
    bf16* lK1 = &Ks[(w * 8 + 4) * 128];

    // V^T staging: instr i covers d-rows (w*2+i)*16..+15; lane d = +L>>2,
    // stored pos p=L&3 holds logical chunk p^(d&3)^((d>>2)&3).
    const int vd0 = (w * 2) * 16 + (L >> 2);
    const int vd1 = vd0 + 16;
    const bf16* vbase = vt + (size_t)((b * KHc + kh) * Hc) * Tc;
    const bf16* gV0 = vbase + (size_t)vd0 * Tc + (((L & 3) ^ (vd0 & 3) ^ ((vd0 >> 2) & 3)) * 8);
    const bf16* gV1 = vbase + (size_t)vd1 * Tc + (((L & 3) ^ (vd1 & 3) ^ ((vd1 >> 2) & 3)) * 8);
    bf16* lV0 = &VT[(w * 2) * 512];
    bf16* lV1 = &VT[(w * 2 + 1) * 512];

    // Loop-invariant swizzled fragment pointers.
    const bf16* kf[4][2];
#pragma unroll
    for (int c = 0; c < 4; ++c) {
        kf[c][0] = &Ks[lid * 128        + (((c * 4 + quad) ^ lid) * 8)];
        kf[c][1] = &Ks[(16 + lid) * 128 + (((c * 4 + quad) ^ lid) * 8)];
    }
    const int vpos = (quad ^ (lid & 3) ^ ((lid >> 2) & 3)) * 8;
    const bf16* vf[8];
#pragma unroll
    for (int cg = 0; cg < 8; ++cg) vf[cg] = &VT[(cg * 16 + lid) * 32 + vpos];

    floatx4 oacc[8] = {};
    float lsum[4] = {0.f, 0.f, 0.f, 0.f};
    const int sEnd = tblk * 64 + 64;

    for (int s0 = 0; s0 < sEnd; s0 += 32) {
        __syncthreads();                         // prior-iter LDS reads done
        gload_lds16(gK0 + (size_t)s0 * kstride, lK0);
        gload_lds16(gK1 + (size_t)s0 * kstride, lK1);
        gload_lds16(gV0 + s0, lV0);
        gload_lds16(gV1 + s0, lV1);
        __syncthreads();                         // DMA drained

        // ---- QK^T: 16 q x 32 keys ----
        floatx4 sc0 = {0.f, 0.f, 0.f, 0.f}, sc1 = {0.f, 0.f, 0.f, 0.f};
#pragma unroll
        for (int c = 0; c < 4; ++c) {
            sc0 = MFMA16(aqf[c], *(const bf16x8*)kf[c][0], sc0);
            sc1 = MFMA16(aqf[c], *(const bf16x8*)kf[c][1], sc1);
        }

        // ---- mask + exp(shift 16) + P to LDS (C->A layout) ----
#pragma unroll
        for (int r = 0; r < 4; ++r) {
            const int tq  = t0 + quad * 4 + r;
            const int sk0 = s0 + lid, sk1 = s0 + 16 + lid;
            const float p0 = (sk0 <= tq && sk0 >= st)
                               ? __expf(sc0[r] * 0.08838834764831845f - 16.f) : 0.f;
            const float p1 = (sk1 <= tq && sk1 >= st)
                               ? __expf(sc1[r] * 0.08838834764831845f - 16.f) : 0.f;
            lsum[r] += p0 + p1;
            pS[w][quad * 4 + r][lid]      = (bf16)p0;
            pS[w][quad * 4 + r][16 + lid] = (bf16)p1;
        }
        asm volatile("s_waitcnt lgkmcnt(0)" ::: "memory");  // same-wave RAW

        // ---- PV: P (16x32) * V (32x128) ----
        bf16x8 pa = *(const bf16x8*)&pS[w][lid][quad * 8];
#pragma unroll
        for (int cg = 0; cg < 8; ++cg)
            oacc[cg] = MFMA16(pa, *(const bf16x8*)vf[cg], oacc[cg]);
    }

#pragma unroll
    for (int r = 0; r < 4; ++r) {
        lsum[r] += __shfl_xor(lsum[r], 1);
        lsum[r] += __shfl_xor(lsum[r], 2);
        lsum[r] += __shfl_xor(lsum[r], 4);
        lsum[r] += __shfl_xor(lsum[r], 8);
    }

#pragma unroll
    for (int cg = 0; cg < 8; ++cg) {
#pragma unroll
        for (int r = 0; r < 4; ++r) {
            const int t = t0 + quad * 4 + r;
            outp[((size_t)(b * Tc + t) * NHc + n) * Hc + cg * 16 + lid] =
                (bf16)(oacc[cg][r] / lsum[r]);
        }
    }
}

// ---------------------------------------------------------------------------
// Workspace layout (88 MB + 8 B):
//   [0,48M)  wcomb : [wqT;wkT;wvT] (6144 x 4096 bf16). After the QKV GEMM,
//            [0,32M) is overwritten by woT and [32,36M) by vtb (wkT dead).
//   [48,72M) qkvb  : [2048][6144] bf16 (q: 0-4095, k: 4096-5119, v: 5120-6143)
//   [72,88M) xb (bf16 x) -> overlaid by ab (attention out) after QKV GEMM
//   [88M)    start[B]
// ---------------------------------------------------------------------------
extern "C" void kernel_launch(void* const* d_in, const int* in_sizes, int n_in,
                              void* d_out, int out_size, void* d_ws, size_t ws_size,
                              hipStream_t stream) {
    const float* x       = (const float*)d_in[0];
    const float* wq      = (const float*)d_in[1];
    const float* wk      = (const float*)d_in[2];
    const float* wv      = (const float*)d_in[3];
    const float* wo      = (const float*)d_in[4];
    const float* q_scale = (const float*)d_in[5];
    const float* k_scale = (const float*)d_in[6];
    const int*   seg     = (const int*)d_in[9];
    float*       out     = (float*)d_out;

    char* ws = (char*)d_ws;
    bf16* wcomb = (bf16*)(ws);
    bf16* vtb   = (bf16*)(ws + (32ull << 20));      // overlay: dead wkT region
    bf16* qkvb  = (bf16*)(ws + (48ull << 20));
    bf16* xb    = (bf16*)(ws + (72ull << 20));
    bf16* ab    = xb;                               // overlay (xb dead by then)
    int*  stb   = (int*) (ws + (88ull << 20));

    seg_scan<<<1, 64, 0, stream>>>(seg, stb);

    cvt_f32_bf16<<<(Bc * Tc * Dc) / (256 * 8), 256, 0, stream>>>(x, xb);

    transpose_cvt<<<dim3(64, 64), 256, 0, stream>>>(wq, wcomb, Dc, NHc * Hc);
    transpose_cvt<<<dim3(16, 64), 256, 0, stream>>>(wk, wcomb + (size_t)4096 * Dc, Dc, KHc * Hc);
    transpose_cvt<<<dim3(16, 64), 256, 0, stream>>>(wv, wcomb + (size_t)5120 * Dc, Dc, KHc * Hc);

    // Fused QKV projection: [2048 x 4096] * [6144 x 4096]^T -> [2048 x 6144]
    // 128x192-tile ring-3 kernel: 32 x 16 = 512 wg = exactly 2 blocks/CU.
    gemm_ring192<bf16><<<dim3(32, 16), 256, 0, stream>>>(xb, wcomb, qkvb,
                                                         Bc * Tc, Dc, 6144);

    rms_rope<<<(Bc * Tc * NHc) / 4, 256, 0, stream>>>(qkvb, q_scale, stb, NHc, 6144);
    rms_rope<<<(Bc * Tc * KHc) / 4, 256, 0, stream>>>(qkvb + 4096, k_scale, stb, KHc, 6144);

    v_transpose<<<dim3(Tc / 32, Bc * KHc), 256, 0, stream>>>(qkvb + 5120, vtb, 6144);

    // woT into wcomb[0,32M) (wqT dead after QKV GEMM).
    transpose_cvt<<<dim3(64, 64), 256, 0, stream>>>(wo, wcomb, NHc * Hc, Dc);

    attn_kernel<<<dim3(Tc / 64, NHc, Bc), 256, 0, stream>>>(
        qkvb, qkvb + 4096, vtb, ab, stb, 6144, 6144);

    // Out projection: [2048 x 4096] * [4096 x 4096]^T -> [2048 x 4096] fp32
    gemm128<float><<<dim3(32, 16), 256, 0, stream>>>(ab, wcomb, out,
                                                     Bc * Tc, NHc * Hc, Dc);
}

// Round 5
// 499.299 us; speedup vs baseline: 1.0711x; 1.0429x over previous
//
#include <hip/hip_runtime.h>

// ---------------------------------------------------------------------------
// Fixed problem shape: B=2, T=1024, D=4096, N=32 q-heads, KH=8 kv-heads, H=128.
// ---------------------------------------------------------------------------
constexpr int Bc  = 2;
constexpr int Tc  = 1024;
constexpr int Dc  = 4096;
constexpr int NHc = 32;
constexpr int KHc = 8;
constexpr int Hc  = 128;

typedef __bf16 bf16;
typedef bf16  bf16x4  __attribute__((ext_vector_type(4)));
typedef bf16  bf16x8  __attribute__((ext_vector_type(8)));
typedef float floatx4 __attribute__((ext_vector_type(4)));

#define MFMA16(a, b, c) __builtin_amdgcn_mfma_f32_16x16x32_bf16((a), (b), (c), 0, 0, 0)

// Async global->LDS DMA, 16 B/lane. LDS dest is wave-uniform base + lane*16
// (m104/m108) — lane->LDS map fixed; we pick each lane's GLOBAL source to
// implement swizzled tile layouts for free.
__device__ __forceinline__ void gload_lds16(const bf16* g, bf16* l) {
    __builtin_amdgcn_global_load_lds(
        (const __attribute__((address_space(1))) void*)g,
        (__attribute__((address_space(3))) void*)l, 16, 0, 0);
}

// ---------------------------------------------------------------------------
// start[b] = index of first nonzero segment id.
// ---------------------------------------------------------------------------
__global__ void seg_scan(const int* __restrict__ seg, int* __restrict__ start) {
    int b = threadIdx.x;
    if (b >= Bc) return;
    int f = 0;
    for (int t = 0; t < Tc; ++t) {
        if (seg[b * Tc + t] != 0) { f = t; break; }
    }
    start[b] = f;
}

// ---------------------------------------------------------------------------
// fp32 -> bf16 convert (x pre-pass), 8 elems/thread vectorized.
// ---------------------------------------------------------------------------
__global__ __launch_bounds__(256) void cvt_f32_bf16(const float* __restrict__ in,
                                                    bf16* __restrict__ out) {
    const size_t i = ((size_t)blockIdx.x * 256 + threadIdx.x) * 8;
    float4 f0 = *(const float4*)(in + i);
    float4 f1 = *(const float4*)(in + i + 4);
    bf16x8 v;
    v[0] = (bf16)f0.x; v[1] = (bf16)f0.y; v[2] = (bf16)f0.z; v[3] = (bf16)f0.w;
    v[4] = (bf16)f1.x; v[5] = (bf16)f1.y; v[6] = (bf16)f1.z; v[7] = (bf16)f1.w;
    *(bf16x8*)(out + i) = v;
}

// ---------------------------------------------------------------------------
// Transpose + fp32->bf16 convert: out[C x R] = in[R x C]^T. 64x64 tile,
// float4 loads (16 B/lane), bf16x4 stores (8 B/lane), +1 pad (2-way banks).
// ---------------------------------------------------------------------------
__global__ __launch_bounds__(256) void transpose_cvt(const float* __restrict__ in,
                                                     bf16* __restrict__ out,
                                                     int R, int C) {
    __shared__ float tile[64][65];
    const int c0 = blockIdx.x * 64, r0 = blockIdx.y * 64;
    const int tx = threadIdx.x & 15, ty = threadIdx.x >> 4;   // 16 x 16
#pragma unroll
    for (int i = 0; i < 4; ++i) {
        float4 f = *(const float4*)&in[(size_t)(r0 + ty * 4 + i) * C + c0 + tx * 4];
        tile[ty * 4 + i][tx * 4 + 0] = f.x;
        tile[ty * 4 + i][tx * 4 + 1] = f.y;
        tile[ty * 4 + i][tx * 4 + 2] = f.z;
        tile[ty * 4 + i][tx * 4 + 3] = f.w;
    }
    __syncthreads();
#pragma unroll
    for (int i = 0; i < 4; ++i) {
        const int cc = ty * 4 + i;
        bf16x4 v;
        v[0] = (bf16)tile[tx * 4 + 0][cc];
        v[1] = (bf16)tile[tx * 4 + 1][cc];
        v[2] = (bf16)tile[tx * 4 + 2][cc];
        v[3] = (bf16)tile[tx * 4 + 3][cc];
        *(bf16x4*)&out[(size_t)(c0 + cc) * R + r0 + tx * 4] = v;
    }
}

// ---------------------------------------------------------------------------
// V transpose: src = qkvb v-columns (strided rows), dst[b][kh][d][t] dense.
// Per block: one (b,kh), 32 t x 128 d tile.
// ---------------------------------------------------------------------------
__global__ __launch_bounds__(256) void v_transpose(const bf16* __restrict__ src,
                                                   bf16* __restrict__ dst,
                                                   int srcstride) {
    __shared__ bf16 tl[32][136];                 // 272B rows: 16B-aligned
    const int bk = blockIdx.y;                   // b*KHc + kh
    const int b = bk / KHc, kh = bk % KHc;
    const int t0 = blockIdx.x * 32;
    const int tid = threadIdx.x;
    {
        const int j = tid >> 3;                  // t row 0..31
        const int c = tid & 7;                   // d chunk of 16
        const bf16* p = src + (size_t)(b * Tc + t0 + j) * srcstride + kh * Hc + c * 16;
        *(bf16x8*)&tl[j][c * 16]     = *(const bf16x8*)p;
        *(bf16x8*)&tl[j][c * 16 + 8] = *(const bf16x8*)(p + 8);
    }
    __syncthreads();
    {
        const int d = tid >> 1;                  // 0..127
        const int toff = (tid & 1) * 16;
        bf16x8 v0, v1;
#pragma unroll
        for (int k = 0; k < 8; ++k) v0[k] = tl[toff + k][d];
#pragma unroll
        for (int k = 0; k < 8; ++k) v1[k] = tl[toff + 8 + k][d];
        bf16* o = dst + ((size_t)bk * Hc + d) * Tc + t0 + toff;
        *(bf16x8*)o       = v0;
        *(bf16x8*)(o + 8) = v1;
    }
}

// ---------------------------------------------------------------------------
// R8: 128x128-tile 4-wave ring-pipelined GEMM, 2 blocks/CU (out-projection).
//   C[M x N] = A[M x K] * Bt[N x K]^T, bf16 in, OT out. BK=32, ring-3 LDS
//   (3 x 16 KB = 48 KB => two blocks/CU co-resident; m114 cross-block
//   MFMA/memory co-scheduling covers barrier drains).
// Per tile: 4 x global_load_lds(16B)/thread (A:2, B:2, all uniform).
// Sync ledger (same proof as R7 ring192, 5->4 loads/tile):
//   - iter t stages tile t+2 into slot (cur+2)%3 == iter t-1's slot; its
//     reads completed before iter t-1's MFMAs (data-dep lgkmcnt) which
//     precede its closing barrier. No race.
//   - end-of-iter vmcnt(4): outstanding <= {t+1:4, t+2:4}; waiting to 4
//     drains tile t+1 (oldest). Never vmcnt(0) in-loop (T4).
//   - raw s_barrier (no compiler drain); post-loop vmcnt(0) before endpgm.
// Requires: M%128==0, N%128==0, K%32==0, K/32 >= 3.
// ---------------------------------------------------------------------------
template <typename OT>
__global__ __launch_bounds__(256, 2) void gemm_ring128(const bf16* __restrict__ A,
                                                       const bf16* __restrict__ Bt,
                                                       OT* __restrict__ C,
                                                       int M, int K, int N) {
    // slot layout: A[128][32] at elem 0, B[128][32] at elem 4096. 8192/slot.
    __shared__ alignas(16) bf16 ring[3][8192];
    const int m0 = blockIdx.y * 128, n0 = blockIdx.x * 128;
    const int tid = threadIdx.x;
    const int w = tid >> 6, L = tid & 63, quad = L >> 4, lid = L & 15;
    const int wr = w >> 1, wc = w & 1;           // 2 x 2 wave grid

    // ---- staging geometry: 4 x global_load_lds(16B) per thread per tile ----
    // Each instr covers 64 rows (256 thr x 16B = 4 KB); row = base + tid>>2,
    // stored chunk c = tid&3 holds global chunk c ^ ((row>>1)&3)
    // (involution; linear LDS dest + inverse-swizzled source, rule #21).
    const int srow = tid >> 2;                               // 0..63
    const int schk = ((tid & 3) ^ ((tid >> 3) & 3)) * 8;     // swizzled k-chunk
    const bf16* gA = A  + (size_t)(m0 + srow) * K + schk;
    const bf16* gB = Bt + (size_t)(n0 + srow) * K + schk;
    const size_t K64 = (size_t)64 * K;
    // wave-uniform LDS bases (elems within slot)
    const int ldsA0 = (w * 16) * 32;
    const int ldsA1 = (64 + w * 16) * 32;
    const int ldsB0 = 4096 + (w * 16) * 32;
    const int ldsB1 = 4096 + (64 + w * 16) * 32;

    // ---- fragment offsets (swizzled read side, 2-way banks = free) ----
    int offA[4], offB[4];
#pragma unroll
    for (int m = 0; m < 4; ++m) {
        const int row = wr * 64 + m * 16 + lid;
        offA[m] = row * 32 + ((quad ^ ((row >> 1) & 3)) * 8);
    }
#pragma unroll
    for (int n = 0; n < 4; ++n) {
        const int row = wc * 64 + n * 16 + lid;
        offB[n] = 4096 + row * 32 + ((quad ^ ((row >> 1) & 3)) * 8);
    }

    const int NT = K >> 5;                       // K/32

    auto stage = [&](int kt, int sl) {           // kt pre-wrapped; sl = slot
        bf16* sb = ring[sl];
        const size_t ko = (size_t)kt << 5;
        gload_lds16(gA + ko,       sb + ldsA0);
        gload_lds16(gA + K64 + ko, sb + ldsA1);
        gload_lds16(gB + ko,       sb + ldsB0);
        gload_lds16(gB + K64 + ko, sb + ldsB1);
    };

    // prologue: tiles 0,1 in flight; wait tile 0 (4 = tile 1 outstanding)
    stage(0, 0); stage(1, 1);
    asm volatile("s_waitcnt vmcnt(4)" ::: "memory");
    __builtin_amdgcn_s_barrier();
    __builtin_amdgcn_sched_barrier(0);

    floatx4 acc[4][4] = {};
    int cur = 0;                                 // slot of tile t

    for (int t = 0; t < NT; ++t) {
        int ts = t + 2; if (ts >= NT) ts -= NT;  // wrap: tail re-stages 0,1
        int ss = cur + 2; if (ss >= 3) ss -= 3;  // slot of tile t+2
        stage(ts, ss);                           // (wrap data never consumed)

        const bf16* sb = ring[cur];
        bf16x8 af[4], bfr[4];
#pragma unroll
        for (int m = 0; m < 4; ++m) af[m]  = *(const bf16x8*)(sb + offA[m]);
#pragma unroll
        for (int n = 0; n < 4; ++n) bfr[n] = *(const bf16x8*)(sb + offB[n]);

        __builtin_amdgcn_s_setprio(1);
#pragma unroll
        for (int m = 0; m < 4; ++m)
#pragma unroll
            for (int n = 0; n < 4; ++n)
                acc[m][n] = MFMA16(af[m], bfr[n], acc[m][n]);
        __builtin_amdgcn_s_setprio(0);

        asm volatile("s_waitcnt vmcnt(4)" ::: "memory");  // tile t+1 landed
        __builtin_amdgcn_s_barrier();
        __builtin_amdgcn_sched_barrier(0);
        cur = (cur == 2) ? 0 : cur + 1;
    }

    // Drain remaining LDS-DMAs (wrap-stages) before epilogue/endpgm.
    asm volatile("s_waitcnt vmcnt(0)" ::: "memory");

#pragma unroll
    for (int m = 0; m < 4; ++m) {
#pragma unroll
        for (int r = 0; r < 4; ++r) {
            const size_t row = (size_t)(m0 + wr * 64 + m * 16 + quad * 4 + r);
#pragma unroll
            for (int n = 0; n < 4; ++n)
                C[row * N + (n0 + wc * 64 + n * 16 + lid)] = (OT)acc[m][n][r];
        }
    }
}

// ---------------------------------------------------------------------------
// R7: 128x192-tile 4-wave ring-pipelined GEMM, 2 blocks/CU (QKV projection).
//   Same ledger as gemm_ring128; 5 loads/tile (A:2, B:3), vmcnt(5).
// Requires: M%128==0, N%192==0, K%32==0, K/32 >= 3.
// ---------------------------------------------------------------------------
template <typename OT>
__global__ __launch_bounds__(256, 2) void gemm_ring192(const bf16* __restrict__ A,
                                                       const bf16* __restrict__ Bt,
                                                       OT* __restrict__ C,
                                                       int M, int K, int N) {
    // slot layout: A[128][32] at elem 0, B[192][32] at elem 4096. 10240/slot.
    __shared__ alignas(16) bf16 ring[3][10240];
    const int m0 = blockIdx.y * 128, n0 = blockIdx.x * 192;
    const int tid = threadIdx.x;
    const int w = tid >> 6, L = tid & 63, quad = L >> 4, lid = L & 15;
    const int wr = w >> 1, wc = w & 1;           // 2 x 2 wave grid

    const int srow = tid >> 2;                               // 0..63
    const int schk = ((tid & 3) ^ ((tid >> 3) & 3)) * 8;     // swizzled k-chunk
    const bf16* gA = A  + (size_t)(m0 + srow) * K + schk;
    const bf16* gB = Bt + (size_t)(n0 + srow) * K + schk;
    const size_t K64 = (size_t)64 * K, K128 = (size_t)128 * K;
    const int ldsA0 = (w * 16) * 32;
    const int ldsA1 = (64 + w * 16) * 32;
    const int ldsB0 = 4096 + (w * 16) * 32;
    const int ldsB1 = 4096 + (64 + w * 16) * 32;
    const int ldsB2 = 4096 + (128 + w * 16) * 32;

    int offA[4], offB[6];
#pragma unroll
    for (int m = 0; m < 4; ++m) {
        const int row = wr * 64 + m * 16 + lid;
        offA[m] = row * 32 + ((quad ^ ((row >> 1) & 3)) * 8);
    }
#pragma unroll
    for (int n = 0; n < 6; ++n) {
        const int row = wc * 96 + n * 16 + lid;
        offB[n] = 4096 + row * 32 + ((quad ^ ((row >> 1) & 3)) * 8);
    }

    const int NT = K >> 5;                       // K/32

    auto stage = [&](int kt, int sl) {           // kt pre-wrapped; sl = slot
        bf16* sb = ring[sl];
        const size_t ko = (size_t)kt << 5;
        gload_lds16(gA + ko,         sb + ldsA0);
        gload_lds16(gA + K64 + ko,   sb + ldsA1);
        gload_lds16(gB + ko,         sb + ldsB0);
        gload_lds16(gB + K64 + ko,   sb + ldsB1);
        gload_lds16(gB + K128 + ko,  sb + ldsB2);
    };

    stage(0, 0); stage(1, 1);
    asm volatile("s_waitcnt vmcnt(5)" ::: "memory");
    __builtin_amdgcn_s_barrier();
    __builtin_amdgcn_sched_barrier(0);

    floatx4 acc[4][6] = {};
    int cur = 0;                                 // slot of tile t

    for (int t = 0; t < NT; ++t) {
        int ts = t + 2; if (ts >= NT) ts -= NT;  // wrap: tail re-stages 0,1
        int ss = cur + 2; if (ss >= 3) ss -= 3;  // slot of tile t+2
        stage(ts, ss);                           // (wrap data never consumed)

        const bf16* sb = ring[cur];
        bf16x8 af[4], bfr[6];
#pragma unroll
        for (int m = 0; m < 4; ++m) af[m]  = *(const bf16x8*)(sb + offA[m]);
#pragma unroll
        for (int n = 0; n < 6; ++n) bfr[n] = *(const bf16x8*)(sb + offB[n]);

        __builtin_amdgcn_s_setprio(1);
#pragma unroll
        for (int m = 0; m < 4; ++m)
#pragma unroll
            for (int n = 0; n < 6; ++n)
                acc[m][n] = MFMA16(af[m], bfr[n], acc[m][n]);
        __builtin_amdgcn_s_setprio(0);

        asm volatile("s_waitcnt vmcnt(5)" ::: "memory");  // tile t+1 landed
        __builtin_amdgcn_s_barrier();
        __builtin_amdgcn_sched_barrier(0);
        cur = (cur == 2) ? 0 : cur + 1;
    }

    asm volatile("s_waitcnt vmcnt(0)" ::: "memory");

#pragma unroll
    for (int m = 0; m < 4; ++m) {
#pragma unroll
        for (int r = 0; r < 4; ++r) {
            const size_t row = (size_t)(m0 + wr * 64 + m * 16 + quad * 4 + r);
#pragma unroll
            for (int n = 0; n < 6; ++n)
                C[row * N + (n0 + wc * 96 + n * 16 + lid)] = (OT)acc[m][n][r];
        }
    }
}

// ---------------------------------------------------------------------------
// In-place RMSNorm (+scale) + RoPE; one wave per head-vector (strided buffer).
// ---------------------------------------------------------------------------
__global__ __launch_bounds__(256) void rms_rope(bf16* __restrict__ buf,
                                                const float* __restrict__ scale,
                                                const int* __restrict__ start,
                                                int nheads, int rowstride) {
    const int gid = blockIdx.x * 4 + (threadIdx.x >> 6);
    const int L   = threadIdx.x & 63;
    const int h   = gid % nheads;
    const int t   = (gid / nheads) % Tc;
    const int b   = gid / (nheads * Tc);
    bf16* p = buf + (size_t)(b * Tc + t) * rowstride + h * Hc;

    float x1 = (float)p[L], x2 = (float)p[L + 64];
    float ss = x1 * x1 + x2 * x2;
#pragma unroll
    for (int off = 1; off < 64; off <<= 1) ss += __shfl_xor(ss, off);
    const float inv = 1.f / sqrtf(ss * (1.0f / 128.0f) + 1e-6f);
    const float y1 = scale[L] * x1 * inv;
    const float y2 = scale[L + 64] * x2 * inv;

    const int   pos = t - start[b];
    const float fr  = (float)L * (1.0f / 64.0f);
    const float invf = exp2f(-19.9315686f * fr);   // theta^-fr, theta=1e6
    const float ang = (float)pos * invf;
    float sn, cs;
    sincosf(ang, &sn, &cs);                        // accurate (large args)

    p[L]      = (bf16)(y1 * cs - y2 * sn);
    p[L + 64] = (bf16)(y2 * cs + y1 * sn);
}

// ---------------------------------------------------------------------------
// Causal GQA flash attention, fixed-shift softmax (post-RMSNorm |logit| <=
// 11.3 => p = exp(logit-16), exact after final /sum).
// K tile (32 s x 128 d, natural) and V^T tile (128 d x 32 s) staged via
// global_load_lds with XOR chunk swizzles; shared by all 4 waves.
// ---------------------------------------------------------------------------
__global__ __launch_bounds__(256) void attn_kernel(const bf16* __restrict__ q,
                                                   const bf16* __restrict__ k,
                                                   const bf16* __restrict__ vt,
                                                   bf16* __restrict__ outp,
                                                   const int* __restrict__ start,
                                                   int qstride, int kstride) {
    __shared__ alignas(16) bf16 Ks[32 * 128];    // row s (256 B), swizzled chunks
    __shared__ alignas(16) bf16 VT[128 * 32];    // row d (64 B), swizzled chunks
    __shared__ alignas(16) bf16 pS[4][16][40];   // per-wave P tile

    const int tblk = blockIdx.x, n = blockIdx.y, b = blockIdx.z;
    const int kh   = n >> 2;                     // N/KH = 4
    const int tid  = threadIdx.x, w = tid >> 6, L = tid & 63;
    const int quad = L >> 4, lid = L & 15;
    const int t0   = tblk * 64 + w * 16;
    const int st   = start[b];

    // Q fragments (16 rows x 128 feats) in registers.
    const bf16* qrow = q + (size_t)(b * Tc + t0 + lid) * qstride + n * Hc;
    bf16x8 aqf[4];
#pragma unroll
    for (int c = 0; c < 4; ++c) aqf[c] = *(const bf16x8*)(qrow + c * 32 + quad * 8);

    // K staging: instr i covers rows w*8+4i..+3; lane row = +L>>4, stored
    // chunk p=L&15 holds logical chunk p^(row&15).
    const int kr0 = w * 8 + (L >> 4);
    const int kr1 = kr0 + 4;
    const bf16* gK0 = k + (size_t)(b * Tc + kr0) * kstride + kh * Hc
                        + (((L & 15) ^ (kr0 & 15)) * 8);
    const bf16* gK1 = k + (size_t)(b * Tc + kr1) * kstride + kh * Hc
                        + (((L & 15) ^ (kr1 & 15)) * 8);
    bf16* lK0 = &Ks[(w * 8) * 128];
    bf16* lK1 = &Ks[(w * 8 + 4) * 128];

    // V^T staging: instr i covers d-rows (w*2+i)*16..+15; lane d = +L>>2,
    // stored pos p=L&3 holds logical chunk p^(d&3)^((d>>2)&3).
    const int vd0 = (w * 2) * 16 + (L >> 2);
    const int vd1 = vd0 + 16;
    const bf16* vbase = vt + (size_t)((b * KHc + kh) * Hc) * Tc;
    const bf16* gV0 = vbase + (size_t)vd0 * Tc + (((L & 3) ^ (vd0 & 3) ^ ((vd0 >> 2) & 3)) * 8);
    const bf16* gV1 = vbase + (size_t)vd1 * Tc + (((L & 3) ^ (vd1 & 3) ^ ((vd1 >> 2) & 3)) * 8);
    bf16* lV0 = &VT[(w * 2) * 512];
    bf16* lV1 = &VT[(w * 2 + 1) * 512];

    // Loop-invariant swizzled fragment pointers.
    const bf16* kf[4][2];
#pragma unroll
    for (int c = 0; c < 4; ++c) {
        kf[c][0] = &Ks[lid * 128        + (((c * 4 + quad) ^ lid) * 8)];
        kf[c][1] = &Ks[(16 + lid) * 128 + (((c * 4 + quad) ^ lid) * 8)];
    }
    const int vpos = (quad ^ (lid & 3) ^ ((lid >> 2) & 3)) * 8;
    const bf16* vf[8];
#pragma unroll
    for (int cg = 0; cg < 8; ++cg) vf[cg] = &VT[(cg * 16 + lid) * 32 + vpos];

    floatx4 oacc[8] = {};
    float lsum[4] = {0.f, 0.f, 0.f, 0.f};
    const int sEnd = tblk * 64 + 64;

    for (int s0 = 0; s0 < sEnd; s0 += 32) {
        __syncthreads();                         // prior-iter LDS reads done
        gload_lds16(gK0 + (size_t)s0 * kstride, lK0);
        gload_lds16(gK1 + (size_t)s0 * kstride, lK1);
        gload_lds16(gV0 + s0, lV0);
        gload_lds16(gV1 + s0, lV1);
        __syncthreads();                         // DMA drained

        // ---- QK^T: 16 q x 32 keys ----
        floatx4 sc0 = {0.f, 0.f, 0.f, 0.f}, sc1 = {0.f, 0.f, 0.f, 0.f};
#pragma unroll
        for (int c = 0; c < 4; ++c) {
            sc0 = MFMA16(aqf[c], *(const bf16x8*)kf[c][0], sc0);
            sc1 = MFMA16(aqf[c], *(const bf16x8*)kf[c][1], sc1);
        }

        // ---- mask + exp(shift 16) + P to LDS (C->A layout) ----
#pragma unroll
        for (int r = 0; r < 4; ++r) {
            const int tq  = t0 + quad * 4 + r;
            const int sk0 = s0 + lid, sk1 = s0 + 16 + lid;
            const float p0 = (sk0 <= tq && sk0 >= st)
                               ? __expf(sc0[r] * 0.08838834764831845f - 16.f) : 0.f;
            const float p1 = (sk1 <= tq && sk1 >= st)
                               ? __expf(sc1[r] * 0.08838834764831845f - 16.f) : 0.f;
            lsum[r] += p0 + p1;
            pS[w][quad * 4 + r][lid]      = (bf16)p0;
            pS[w][quad * 4 + r][16 + lid] = (bf16)p1;
        }
        asm volatile("s_waitcnt lgkmcnt(0)" ::: "memory");  // same-wave RAW

        // ---- PV: P (16x32) * V (32x128) ----
        bf16x8 pa = *(const bf16x8*)&pS[w][lid][quad * 8];
#pragma unroll
        for (int cg = 0; cg < 8; ++cg)
            oacc[cg] = MFMA16(pa, *(const bf16x8*)vf[cg], oacc[cg]);
    }

#pragma unroll
    for (int r = 0; r < 4; ++r) {
        lsum[r] += __shfl_xor(lsum[r], 1);
        lsum[r] += __shfl_xor(lsum[r], 2);
        lsum[r] += __shfl_xor(lsum[r], 4);
        lsum[r] += __shfl_xor(lsum[r], 8);
    }

#pragma unroll
    for (int cg = 0; cg < 8; ++cg) {
#pragma unroll
        for (int r = 0; r < 4; ++r) {
            const int t = t0 + quad * 4 + r;
            outp[((size_t)(b * Tc + t) * NHc + n) * Hc + cg * 16 + lid] =
                (bf16)(oacc[cg][r] / lsum[r]);
        }
    }
}

// ---------------------------------------------------------------------------
// Workspace layout (88 MB + 8 B):
//   [0,48M)  wcomb : [wqT;wkT;wvT] (6144 x 4096 bf16). After the QKV GEMM,
//            [0,32M) is overwritten by woT and [32,36M) by vtb (wkT dead).
//   [48,72M) qkvb  : [2048][6144] bf16 (q: 0-4095, k: 4096-5119, v: 5120-6143)
//   [72,88M) xb (bf16 x) -> overlaid by ab (attention out) after QKV GEMM
//   [88M)    start[B]
// ---------------------------------------------------------------------------
extern "C" void kernel_launch(void* const* d_in, const int* in_sizes, int n_in,
                              void* d_out, int out_size, void* d_ws, size_t ws_size,
                              hipStream_t stream) {
    const float* x       = (const float*)d_in[0];
    const float* wq      = (const float*)d_in[1];
    const float* wk      = (const float*)d_in[2];
    const float* wv      = (const float*)d_in[3];
    const float* wo      = (const float*)d_in[4];
    const float* q_scale = (const float*)d_in[5];
    const float* k_scale = (const float*)d_in[6];
    const int*   seg     = (const int*)d_in[9];
    float*       out     = (float*)d_out;

    char* ws = (char*)d_ws;
    bf16* wcomb = (bf16*)(ws);
    bf16* vtb   = (bf16*)(ws + (32ull << 20));      // overlay: dead wkT region
    bf16* qkvb  = (bf16*)(ws + (48ull << 20));
    bf16* xb    = (bf16*)(ws + (72ull << 20));
    bf16* ab    = xb;                               // overlay (xb dead by then)
    int*  stb   = (int*) (ws + (88ull << 20));

    seg_scan<<<1, 64, 0, stream>>>(seg, stb);

    cvt_f32_bf16<<<(Bc * Tc * Dc) / (256 * 8), 256, 0, stream>>>(x, xb);

    transpose_cvt<<<dim3(64, 64), 256, 0, stream>>>(wq, wcomb, Dc, NHc * Hc);
    transpose_cvt<<<dim3(16, 64), 256, 0, stream>>>(wk, wcomb + (size_t)4096 * Dc, Dc, KHc * Hc);
    transpose_cvt<<<dim3(16, 64), 256, 0, stream>>>(wv, wcomb + (size_t)5120 * Dc, Dc, KHc * Hc);

    // Fused QKV projection: [2048 x 4096] * [6144 x 4096]^T -> [2048 x 6144]
    // 128x192-tile ring-3 kernel: 32 x 16 = 512 wg = exactly 2 blocks/CU.
    gemm_ring192<bf16><<<dim3(32, 16), 256, 0, stream>>>(xb, wcomb, qkvb,
                                                         Bc * Tc, Dc, 6144);

    rms_rope<<<(Bc * Tc * NHc) / 4, 256, 0, stream>>>(qkvb, q_scale, stb, NHc, 6144);
    rms_rope<<<(Bc * Tc * KHc) / 4, 256, 0, stream>>>(qkvb + 4096, k_scale, stb, KHc, 6144);

    v_transpose<<<dim3(Tc / 32, Bc * KHc), 256, 0, stream>>>(qkvb + 5120, vtb, 6144);

    // woT into wcomb[0,32M) (wqT dead after QKV GEMM).
    transpose_cvt<<<dim3(64, 64), 256, 0, stream>>>(wo, wcomb, NHc * Hc, Dc);

    attn_kernel<<<dim3(Tc / 64, NHc, Bc), 256, 0, stream>>>(
        qkvb, qkvb + 4096, vtb, ab, stb, 6144, 6144);

    // Out projection: [2048 x 4096] * [4096 x 4096]^T -> [2048 x 4096] fp32
    // R8: ring-3 128x128 kernel, 32 x 16 = 512 wg = exactly 2 blocks/CU.
    gemm_ring128<float><<<dim3(32, 16), 256, 0, stream>>>(ab, wcomb, out,
                                                          Bc * Tc, NHc * Hc, Dc);
}